// Round 3
// baseline (98.451 us; speedup 1.0000x reference)
//
#include <hip/hip_runtime.h>

#define D 256
#define BM 64
#define BN 64
#define BK 32
#define LDA (BM + 4)
#define LDB (BN + 4)

// ---------------------------------------------------------------------------
// Hx = X @ W^T   (X: [M, D] row-major, W: [D, D] row-major; Hx[i,j] = sum_k X[i,k]*W[j,k])
// f32 vector GEMM, 64x64 tile, 256 threads, 4x4 micro-tile per thread.
// ---------------------------------------------------------------------------
__global__ __launch_bounds__(256) void gemm_xwt(
    const float* __restrict__ X, const float* __restrict__ W,
    float* __restrict__ Hx) {
  __shared__ float As[BK][LDA];   // stored transposed: As[k][m]
  __shared__ float Bs[BK][LDB];   // Bs[k][n]
  const int bm = blockIdx.x * BM;
  const int bn = blockIdx.y * BN;
  const int t = threadIdx.x;
  const int tx = t & 15, ty = t >> 4;   // 16x16 thread grid -> 4x4 micro tile
  const int lrow = t >> 3, lc4 = t & 7; // loader: 32 rows x 8 float4-cols

  float acc[4][4] = {};

  for (int k0 = 0; k0 < D; k0 += BK) {
#pragma unroll
    for (int rr = 0; rr < BM; rr += 32) {
      int r = lrow + rr;
      float4 v = *(const float4*)&X[(size_t)(bm + r) * D + k0 + lc4 * 4];
      As[lc4 * 4 + 0][r] = v.x; As[lc4 * 4 + 1][r] = v.y;
      As[lc4 * 4 + 2][r] = v.z; As[lc4 * 4 + 3][r] = v.w;
    }
#pragma unroll
    for (int rr = 0; rr < BN; rr += 32) {
      int r = lrow + rr;
      float4 v = *(const float4*)&W[(size_t)(bn + r) * D + k0 + lc4 * 4];
      Bs[lc4 * 4 + 0][r] = v.x; Bs[lc4 * 4 + 1][r] = v.y;
      Bs[lc4 * 4 + 2][r] = v.z; Bs[lc4 * 4 + 3][r] = v.w;
    }
    __syncthreads();
#pragma unroll
    for (int kk = 0; kk < BK; ++kk) {
      float4 a4 = *(const float4*)&As[kk][ty * 4];
      float4 b4 = *(const float4*)&Bs[kk][tx * 4];
      float av[4] = {a4.x, a4.y, a4.z, a4.w};
      float bv[4] = {b4.x, b4.y, b4.z, b4.w};
#pragma unroll
      for (int i = 0; i < 4; ++i)
#pragma unroll
        for (int jj = 0; jj < 4; ++jj)
          acc[i][jj] = fmaf(av[i], bv[jj], acc[i][jj]);
    }
    __syncthreads();
  }

#pragma unroll
  for (int i = 0; i < 4; ++i) {
    float4 o = make_float4(acc[i][0], acc[i][1], acc[i][2], acc[i][3]);
    *(float4*)&Hx[(size_t)(bm + ty * 4 + i) * D + bn + tx * 4] = o;
  }
}

// ---------------------------------------------------------------------------
// inv[gov[e]] = e  (inv pre-memset to -1)
// ---------------------------------------------------------------------------
__global__ void scatter_inv(const int* __restrict__ gov, int* __restrict__ inv, int E) {
  int e = blockIdx.x * 256 + threadIdx.x;
  if (e < E) inv[gov[e]] = e;
}

// ---------------------------------------------------------------------------
// One block per output row j (256 threads = 256 cols):
//   h = (j>0 ? Hx[gov[j-1]] : 0)
//   e2 = inv[j]; if e2>=0: d=e2+1; s = Hx[j].a_lo + Hx[d].a_hi;
//                h += (s>0 ? 1 : 1/8192) * Hx[d]
//   out[j] = leaky_relu(h, 0.2)
// ---------------------------------------------------------------------------
__global__ __launch_bounds__(256) void finalize(
    const float* __restrict__ Hx, const float* __restrict__ a,
    const int* __restrict__ gov, const int* __restrict__ inv,
    float* __restrict__ out) {
  const int j = blockIdx.x;
  const int c = threadIdx.x;

  float h = 0.f;
  if (j > 0) {
    int g = gov[j - 1];
    h = Hx[(size_t)g * D + c];
  }

  const int e2 = inv[j];           // block-uniform
  if (e2 >= 0) {
    const int d = e2 + 1;
    const float hd = Hx[(size_t)d * D + c];
    float p = Hx[(size_t)j * D + c] * a[c] + hd * a[D + c];
    // block reduction of p over 256 threads (4 waves)
#pragma unroll
    for (int off = 32; off > 0; off >>= 1) p += __shfl_down(p, off);
    __shared__ float red[4];
    const int lane = threadIdx.x & 63, wv = threadIdx.x >> 6;
    if (lane == 0) red[wv] = p;
    __syncthreads();
    const float s = red[0] + red[1] + red[2] + red[3];
    const float coef = (s > 0.f) ? 1.f : (1.f / 8192.f);
    h += coef * hd;
  }

  out[(size_t)j * D + c] = (h >= 0.f) ? h : 0.2f * h;
}

extern "C" void kernel_launch(void* const* d_in, const int* in_sizes, int n_in,
                              void* d_out, int out_size, void* d_ws, size_t ws_size,
                              hipStream_t stream) {
  const float* x = (const float*)d_in[0];
  const float* W = (const float*)d_in[1];
  const float* a = (const float*)d_in[2];
  const int* gov = (const int*)d_in[4];
  const int E = in_sizes[4];
  const int N = E + 1;   // 8192

  float* Hx = (float*)d_ws;                                        // N*D f32 = 8 MB
  int* inv = (int*)((char*)d_ws + (size_t)N * D * sizeof(float));  // N ints

  hipMemsetAsync(inv, 0xFF, (size_t)N * sizeof(int), stream);      // -1
  hipLaunchKernelGGL(scatter_inv, dim3((E + 255) / 256), dim3(256), 0, stream,
                     gov, inv, E);
  hipLaunchKernelGGL(gemm_xwt, dim3(N / BM, D / BN), dim3(256), 0, stream,
                     x, W, Hx);
  hipLaunchKernelGGL(finalize, dim3(N), dim3(D), 0, stream,
                     Hx, a, gov, inv, (float*)d_out);
}